// Round 6
// baseline (93.975 us; speedup 1.0000x reference)
//
#include <hip/hip_runtime.h>

#define N        384
#define DIM      256
#define D4       (DIM / 4)       // 64 float4 per row
#define CK4      8               // k4 per chunk
#define NCH      8               // chunks: 8*8 = 64 k4 = full row
#define MARGIN_F 0.2f
#define NANCH    2               // anchors per block
#define NBLK     (N / NANCH)     // 192 blocks (all co-resident on 256 CUs)
#define NTHR     (2 * N)         // 768 threads
#define NWAVE    (NTHR / 64)     // 12 waves
#define MAXPOS   64              // labels ~ Binom(384,1/32): mean 12; >14 sigma
#define NSLOT    8               // striped atomic slots (64B apart)

// ---------------------------------------------------------------------------
// r4 skeleton with the serialization attacked (r5 lesson: kernel is latency-
// bound, NOT LDS-throughput-bound — anchors go back to LDS broadcasts):
//
//  * shared-chunk dbuf pipeline: all 768 threads stage one 48KB chunk (8 k4 x
//    384 rows); kgrp0 dots j=0..3, kgrp1 j=4..7 of the SAME chunk. Two
//    buffers -> ONE barrier per chunk: [ds_write(c) | issue loads(c+1) |
//    barrier | dot(c)]. write(c+2->bufA) occurs after barrier(c+1), by which
//    every wave's dot(c from bufA) is done (program order) -> WAR-safe.
//    Chunk-0 loads issue at kernel entry: cold-HBM first touch (the 256MiB
//    harness fill flushes L3 every iteration) overlaps setup.
//  * unified XOR swizzle js^(row&7) on both ds_write and ds_read: b128
//    8-way bank floor on both sides, no pad (reg-staged, so both-sides
//    swizzle is legal).
//  * striped tail: sum/cnt atomicAdd into slot[bid&7] (64B stride) -> 24
//    same-line RMWs instead of 192; last block reduces 16 slots in-wave.
//
// Workspace: 1088B (done @0, sumSlots @64, cntSlots @576) zeroed by memset.
// ---------------------------------------------------------------------------

__global__ __launch_bounds__(NTHR) void triplet_kernel(
    const float4* __restrict__ emb4, const int* __restrict__ labels,
    float* __restrict__ sumSlots, unsigned int* __restrict__ cntSlots,
    unsigned int* __restrict__ done_cnt, float* __restrict__ out)
{
    const int i0   = blockIdx.x * NANCH;
    const int tid  = threadIdx.x;          // 0..767
    const int wave = tid >> 6, lane = tid & 63;
    const int kgrp = (tid >= N) ? 1 : 0;   // which j-half of each chunk
    const int col  = tid - kgrp * N;       // 0..383: column owned

    // staging geometry: slot_i = i*768 + tid -> row = i*96 + (tid>>3),
    // js = tid&7 (same for all i); swz = js ^ (row&7) = (tid&7)^((tid>>3)&7)
    const int rbase = tid >> 3;            // row within i-stripe
    const int js    = tid & 7;
    const int swz   = js ^ (rbase & 7);    // i*96 preserves row&7

    __shared__ float4 ebuf[2][N][CK4];     // 96KB double buffer, swizzled
    __shared__ float  pacc[3][N];          // vv, rd0, rd1 partials from kgrp1
    __shared__ float  Drow[NANCH][N];      // distance rows
    __shared__ float  invA[NANCH], sqA[NANCH];
    __shared__ int    lab[N];
    __shared__ int    posList[NANCH][MAXPOS];
    __shared__ int    posCnt[NANCH];
    __shared__ float        sredS[NWAVE];
    __shared__ unsigned int sredC[NWAVE];
    __shared__ int    isLastSh;

    // ---- issue chunk-0 loads FIRST: first-touch HBM latency hides under setup
    float4 rr[4];
    #pragma unroll
    for (int i = 0; i < 4; ++i)
        rr[i] = emb4[i * (96 * D4) + rbase * D4 + js];

    if (tid < N) lab[tid] = labels[tid];
    if (tid < NANCH) posCnt[tid] = 0;

    // ---- pipelined staged dot: one barrier per chunk
    float vv = 0.0f, rd0 = 0.0f, rd1 = 0.0f;
    const int j0 = kgrp * 4;
    const int sa0 = i0 & 7, sa1 = (i0 + 1) & 7;    // anchor row swizzle keys

    #pragma unroll
    for (int c = 0; c < NCH; ++c) {
        const int cur = c & 1;
        #pragma unroll
        for (int i = 0; i < 4; ++i)                 // write chunk c (vmcnt dep on rr)
            ebuf[cur][i * 96 + rbase][swz] = rr[i];
        if (c + 1 < NCH) {
            #pragma unroll
            for (int i = 0; i < 4; ++i)             // issue chunk c+1 early
                rr[i] = emb4[i * (96 * D4) + rbase * D4 + (c + 1) * CK4 + js];
        }
        __syncthreads();                            // chunk c visible to all
        #pragma unroll
        for (int jj = 0; jj < 4; ++jj) {
            const int j = j0 + jj;
            const float4 v  = ebuf[cur][col][j ^ (col & 7)];  // 8-way floor
            const float4 a0 = ebuf[cur][i0][j ^ sa0];         // broadcast (free)
            const float4 a1 = ebuf[cur][i0 + 1][j ^ sa1];
            vv  += v.x*v.x  + v.y*v.y  + v.z*v.z  + v.w*v.w;
            rd0 += v.x*a0.x + v.y*a0.y + v.z*a0.z + v.w*a0.w;
            rd1 += v.x*a1.x + v.y*a1.y + v.z*a1.z + v.w*a1.w;
        }
    }

    // ---- combine j-halves, publish anchor inv/sq; kgrp1 builds pos lists
    if (kgrp == 1) { pacc[0][col] = vv; pacc[1][col] = rd0; pacc[2][col] = rd1; }
    __syncthreads();

    float inv_j = 0.0f, sq_j = 0.0f;
    if (kgrp == 0) {
        vv  += pacc[0][col];
        rd0 += pacc[1][col];
        rd1 += pacc[2][col];
        inv_j = 1.0f / fmaxf(sqrtf(vv), 1e-12f);
        sq_j  = vv * inv_j * inv_j;         // = ref's sum(e_norm^2) for row j
        if (col == i0)     { invA[0] = inv_j; sqA[0] = sq_j; }
        if (col == i0 + 1) { invA[1] = inv_j; sqA[1] = sq_j; }
    } else {
        const int lj = lab[col];
        #pragma unroll
        for (int a = 0; a < NANCH; ++a) {
            const int ia = i0 + a;
            if (lj == lab[ia] && col != ia)
                posList[a][atomicAdd(&posCnt[a], 1)] = col;
        }
    }
    __syncthreads();

    if (kgrp == 0) {                        // finalize distance rows
        float d2 = fmaxf(sqA[0] + sq_j - 2.0f * (rd0 * (invA[0] * inv_j)), 0.0f);
        Drow[0][col] = (d2 > 0.0f) ? sqrtf(d2) : 0.0f;  // ref: sqrt(where(pos,d2,1))*pos
        d2       = fmaxf(sqA[1] + sq_j - 2.0f * (rd1 * (invA[1] * inv_j)), 0.0f);
        Drow[1][col] = (d2 > 0.0f) ? sqrtf(d2) : 0.0f;
    }
    __syncthreads();

    // ---- semihard accumulation; thread owns (negative = col, anchor = kgrp)
    float        lsum = 0.0f;
    unsigned int lcnt = 0u;
    {
        const int a  = kgrp;
        const int li = lab[i0 + a];
        if (lab[col] != li) {
            const float dk = Drow[a][col];     // an
            const int   np = posCnt[a];        // ~11 positives
            for (int p = 0; p < np; ++p) {
                const float tm = dk - Drow[a][posList[a][p]];   // an - ap
                if (tm > 0.0f && tm <= MARGIN_F) {
                    const float l = MARGIN_F - tm;              // max(MARGIN-tm,0)
                    lsum += l;
                    if (l > 0.0f) lcnt++;                       // strict losses>0
                }
            }
        }
    }

    // ---- block reduce
    #pragma unroll
    for (int off = 32; off > 0; off >>= 1) {
        lsum += __shfl_down(lsum, off, 64);
        lcnt += __shfl_down(lcnt, off, 64);
    }
    if (lane == 0) { sredS[wave] = lsum; sredC[wave] = lcnt; }
    __syncthreads();

    // ---- striped device accumulate + done
    if (tid == 0) {
        float        S = 0.0f;
        unsigned int C = 0u;
        #pragma unroll
        for (int w = 0; w < NWAVE; ++w) { S += sredS[w]; C += sredC[w]; }
        if (S != 0.0f || C != 0u) {
            atomicAdd(&sumSlots[(blockIdx.x & (NSLOT - 1)) * 16], S);  // 64B stride
            atomicAdd(&cntSlots[(blockIdx.x & (NSLOT - 1)) * 16], C);
        }
        __threadfence();                        // order adds before done++
        const unsigned int prev = atomicAdd(done_cnt, 1);
        isLastSh = (prev == NBLK - 1) ? 1 : 0;
    }
    __syncthreads();

    // ---- last block: reduce the 8+8 slots (atomic reads = device-coherent)
    if (isLastSh && wave == 0) {
        float        s = 0.0f;
        unsigned int c = 0u;
        if (lane < NSLOT) {
            s = atomicAdd(&sumSlots[lane * 16], 0.0f);
            c = atomicAdd(&cntSlots[lane * 16], 0u);
        }
        #pragma unroll
        for (int off = 4; off > 0; off >>= 1) {
            s += __shfl_down(s, off, 64);
            c += __shfl_down(c, off, 64);
        }
        if (lane == 0) out[0] = (c > 0u) ? (s / (float)c) : 0.0f;
    }
}

extern "C" void kernel_launch(void* const* d_in, const int* in_sizes, int n_in,
                              void* d_out, int out_size, void* d_ws, size_t ws_size,
                              hipStream_t stream) {
    const float4* emb4   = (const float4*)d_in[0];   // (384, 256) fp32
    const int*    labels = (const int*)d_in[1];      // (384,) int32
    float*        out    = (float*)d_out;            // scalar fp32

    unsigned int* done_cnt = (unsigned int*)d_ws;                     // @0
    float*        sumSlots = (float*)((char*)d_ws + 64);              // 8 x 64B
    unsigned int* cntSlots = (unsigned int*)((char*)d_ws + 576);      // 8 x 64B

    hipMemsetAsync(d_ws, 0, 1088, stream);         // zero done + slots (graph-legal)
    triplet_kernel<<<NBLK, NTHR, 0, stream>>>(emb4, labels,
                                              sumSlots, cntSlots, done_cnt, out);
}

// Round 8
// 73.662 us; speedup vs baseline: 1.2758x; 1.2758x over previous
//
#include <hip/hip_runtime.h>

#define N        384
#define DIM      256
#define D4       (DIM / 4)       // 64 float4 per row
#define CHUNK_K4 8               // k4 staged per chunk
#define NCHUNK   4               // chunks per k-half: 4*8 = 32 k4 = half of D4
#define MARGIN_F 0.2f
#define NANCH    2               // anchors per block
#define NBLK     (N / NANCH)     // 192 blocks
#define NTHR     (2 * N)         // 768 threads: split-K x2 over 384 columns
#define NWAVE    (NTHR / 64)     // 12 waves
#define MAXPOS   64              // labels ~ Binom(384,1/32): mean 12; >14 sigma
#define LROW     (CHUNK_K4 + 1)  // padded LDS row stride in float4 (bank floor)

// ---------------------------------------------------------------------------
// EXACT revert to the r4 kernel (measured 72.529us, absmax 0.0) — the best
// verified configuration. (r7 attempt of this same source hit an infra
// failure: "container failed twice"; resubmitting unchanged.)
// Post-r4 experiments all regressed:
//   r5: anchors via SGPR + global_load_lds staging  -> 77.0  (+4.5)
//   r6: shared-chunk 1-barrier dbuf pipeline        -> 94.0  (+21.5)
//   r1: de-contended per-block atomic tail          -> +2.6 in r0 context
// Lesson: the r4 schedule (8 loads in flight/thread, two independent k-group
// staging streams, 2 barriers/chunk) hides load latency better than the
// "improvements"; the remaining dur_us is dominated by the harness's 256MiB
// fill (~40us @ 84% HBM) + reset-restore dispatch floor, not by this kernel.
//
//   stage/dot: kgrp g owns k4 in [g*32, g*32+32), staged in 4 chunks of 8 k4
//              (48KB, coalesced 128B runs). Thread-per-column reads its column
//              (padded stride -> bank floor) + 2 anchor rows (broadcast, free)
//              and accumulates vv, rd0, rd1 IN-LANE (no shuffles — r2 lesson).
//   combine:   kgrp1 -> pacc, kgrp0 adds, computes inv_j/sq_j analytically
//              (dot_norm = rd*inv_i*inv_j). kgrp1 builds positive lists.
//   stage C:   thread owns (negative=col, anchor=kgrp).
//   tail:      r0 contended single-line atomics + last-block finalize.
// ---------------------------------------------------------------------------

__global__ __launch_bounds__(NTHR) void triplet_kernel(
    const float4* __restrict__ emb4, const int* __restrict__ labels,
    float* __restrict__ accum_sum, unsigned int* __restrict__ accum_cnt,
    unsigned int* __restrict__ done_cnt, float* __restrict__ out)
{
    const int i0   = blockIdx.x * NANCH;
    const int tid  = threadIdx.x;          // 0..767
    const int wave = tid >> 6, lane = tid & 63;
    const int kgrp = (tid >= N) ? 1 : 0;   // which k-half this thread sums
    const int col  = tid - kgrp * N;       // 0..383: column owned

    __shared__ float4 ebuf[2][N][LROW];    // 110.6 KB: one chunk per kgrp
    __shared__ float  pacc[3][N];          // vv, rd0, rd1 partials from kgrp1
    __shared__ float  Drow[NANCH][N];      // distance rows
    __shared__ float  invA[NANCH], sqA[NANCH];
    __shared__ int    lab[N];
    __shared__ int    posList[NANCH][MAXPOS];
    __shared__ int    posCnt[NANCH];
    __shared__ float        sredS[NWAVE];
    __shared__ unsigned int sredC[NWAVE];

    if (tid < N) lab[tid] = labels[tid];
    if (tid < NANCH) posCnt[tid] = 0;

    // ---- staged dot loop: 32 coalesced global loads + 4x(write|read) chunks
    float vv = 0.0f, rd0 = 0.0f, rd1 = 0.0f;
    const int kbase = kgrp * (NCHUNK * CHUNK_K4);    // 0 or 32

    for (int c = 0; c < NCHUNK; ++c) {
        const int kk0 = kbase + c * CHUNK_K4;
        #pragma unroll
        for (int i = 0; i < 8; ++i) {       // 8 float4/thread, 128B runs/8 lanes
            const int s   = i * N + col;    // 0..3071
            const int row = s >> 3, j = s & 7;
            ebuf[kgrp][row][j] = emb4[row * D4 + kk0 + j];
        }
        __syncthreads();
        #pragma unroll
        for (int j = 0; j < CHUNK_K4; ++j) {
            const float4 v  = ebuf[kgrp][col][j];      // bank-floor column read
            const float4 a0 = ebuf[kgrp][i0][j];       // broadcast (free)
            const float4 a1 = ebuf[kgrp][i0 + 1][j];
            vv  += v.x*v.x  + v.y*v.y  + v.z*v.z  + v.w*v.w;
            rd0 += v.x*a0.x + v.y*a0.y + v.z*a0.z + v.w*a0.w;
            rd1 += v.x*a1.x + v.y*a1.y + v.z*a1.z + v.w*a1.w;
        }
        __syncthreads();
    }

    // ---- combine k-halves, publish anchor inv/sq; kgrp1 builds pos lists
    if (kgrp == 1) { pacc[0][col] = vv; pacc[1][col] = rd0; pacc[2][col] = rd1; }
    __syncthreads();

    float inv_j = 0.0f, sq_j = 0.0f;
    if (kgrp == 0) {
        vv  += pacc[0][col];
        rd0 += pacc[1][col];
        rd1 += pacc[2][col];
        inv_j = 1.0f / fmaxf(sqrtf(vv), 1e-12f);
        sq_j  = vv * inv_j * inv_j;         // = ref's sum(e_norm^2) for row j
        if (col == i0)     { invA[0] = inv_j; sqA[0] = sq_j; }
        if (col == i0 + 1) { invA[1] = inv_j; sqA[1] = sq_j; }
    } else {
        const int lj = lab[col];
        #pragma unroll
        for (int a = 0; a < NANCH; ++a) {
            const int ia = i0 + a;
            if (lj == lab[ia] && col != ia)
                posList[a][atomicAdd(&posCnt[a], 1)] = col;
        }
    }
    __syncthreads();

    if (kgrp == 0) {                        // finalize distance rows
        float d2 = fmaxf(sqA[0] + sq_j - 2.0f * (rd0 * (invA[0] * inv_j)), 0.0f);
        Drow[0][col] = (d2 > 0.0f) ? sqrtf(d2) : 0.0f;  // ref: sqrt(where(pos,d2,1))*pos
        d2       = fmaxf(sqA[1] + sq_j - 2.0f * (rd1 * (invA[1] * inv_j)), 0.0f);
        Drow[1][col] = (d2 > 0.0f) ? sqrtf(d2) : 0.0f;
    }
    __syncthreads();

    // ---- semihard accumulation; thread owns (negative = col, anchor = kgrp)
    float        lsum = 0.0f;
    unsigned int lcnt = 0u;
    {
        const int a  = kgrp;
        const int li = lab[i0 + a];
        if (lab[col] != li) {
            const float dk = Drow[a][col];     // an
            const int   np = posCnt[a];        // ~11 positives
            for (int p = 0; p < np; ++p) {
                const float tm = dk - Drow[a][posList[a][p]];   // an - ap
                if (tm > 0.0f && tm <= MARGIN_F) {
                    const float l = MARGIN_F - tm;              // max(MARGIN-tm,0)
                    lsum += l;
                    if (l > 0.0f) lcnt++;                       // strict losses>0
                }
            }
        }
    }

    // ---- block reduce, device accumulate, last-block finalize
    #pragma unroll
    for (int off = 32; off > 0; off >>= 1) {
        lsum += __shfl_down(lsum, off, 64);
        lcnt += __shfl_down(lcnt, off, 64);
    }
    if (lane == 0) { sredS[wave] = lsum; sredC[wave] = lcnt; }
    __syncthreads();

    if (tid == 0) {
        float        S = 0.0f;
        unsigned int C = 0u;
        #pragma unroll
        for (int w = 0; w < NWAVE; ++w) { S += sredS[w]; C += sredC[w]; }
        if (S != 0.0f || C != 0u) {
            atomicAdd(accum_sum, S);
            atomicAdd(accum_cnt, C);
        }
        __threadfence();                        // order adds before done++
        const unsigned int prev = atomicAdd(done_cnt, 1);
        if (prev == NBLK - 1) {                 // last block computes the mean
            const float        Sall = atomicAdd(accum_sum, 0.0f);
            const unsigned int Call = atomicAdd(accum_cnt, 0u);
            out[0] = (Call > 0u) ? (Sall / (float)Call) : 0.0f;
        }
    }
}

extern "C" void kernel_launch(void* const* d_in, const int* in_sizes, int n_in,
                              void* d_out, int out_size, void* d_ws, size_t ws_size,
                              hipStream_t stream) {
    const float4* emb4   = (const float4*)d_in[0];   // (384, 256) fp32
    const int*    labels = (const int*)d_in[1];      // (384,) int32
    float*        out    = (float*)d_out;            // scalar fp32

    float*        accum_sum = (float*)d_ws;                    // [0]
    unsigned int* accum_cnt = (unsigned int*)accum_sum + 1;    // [1]
    unsigned int* done_cnt  = (unsigned int*)accum_sum + 2;    // [2]

    hipMemsetAsync(d_ws, 0, 16, stream);           // zero sum/cnt/done (graph-legal)
    triplet_kernel<<<NBLK, NTHR, 0, stream>>>(emb4, labels,
                                              accum_sum, accum_cnt, done_cnt, out);
}